// Round 6
// baseline (220.267 us; speedup 1.0000x reference)
//
#include <hip/hip_runtime.h>
#include <hip/hip_bf16.h>
#include <stdint.h>

// Problem: B=2, S=4096, D=1024, H=8, DH=128, W=1024, nb=4, M=B*S=8192
// Pipeline: convert/transpose -> GEMM1 (256^2 8-phase, 16 waves, qkv -> Q/K + V^T)
//           -> flash attention (counted-vmcnt dbuf) -> GEMM2 (+bias+residual)
//           -> in-place LayerNorm.

typedef float f32x4 __attribute__((ext_vector_type(4)));
typedef __bf16 bf16x8 __attribute__((ext_vector_type(8)));

static __device__ __forceinline__ unsigned short f2bf(float f) {
    unsigned int u = __builtin_bit_cast(unsigned int, f);
    u += 0x7fffu + ((u >> 16) & 1u);
    return (unsigned short)(u >> 16);
}

static __device__ __forceinline__ unsigned cvt_pk_bf16(float lo, float hi) {
    unsigned r;
    asm("v_cvt_pk_bf16_f32 %0, %1, %2" : "=v"(r) : "v"(lo), "v"(hi));
    return r;
}

static __device__ __forceinline__ void gload_lds16(const void* g, void* l) {
    __builtin_amdgcn_global_load_lds(
        (__attribute__((address_space(1))) void*)(g),
        (__attribute__((address_space(3))) void*)(l), 16, 0, 0);
}

#define VMCNT(n) asm volatile("s_waitcnt vmcnt(" #n ")" ::: "memory")
#define SB() __builtin_amdgcn_sched_barrier(0)

// ---------------- convert f32 -> bf16 ----------------
__global__ __launch_bounds__(256) void k_convert(const float* __restrict__ in,
                                                 unsigned short* __restrict__ out,
                                                 int n4) {
    int i = blockIdx.x * 256 + threadIdx.x;
    if (i >= n4) return;
    float4 v = ((const float4*)in)[i];
    ushort4 o;
    o.x = f2bf(v.x); o.y = f2bf(v.y); o.z = f2bf(v.z); o.w = f2bf(v.w);
    ((ushort4*)out)[i] = o;
}

// ---------------- transpose f32 [R][C] -> bf16 [C][R] ----------------
__global__ __launch_bounds__(256) void k_transpose(const float* __restrict__ in,
                                                   unsigned short* __restrict__ out,
                                                   int R, int C) {
    __shared__ float tile[64][65];
    const int rt = blockIdx.y * 64, ct = blockIdx.x * 64;
    const int t = threadIdx.x;
#pragma unroll
    for (int i = 0; i < 4; ++i) {
        int fid = i * 256 + t;
        int r = fid >> 4;
        int c = (fid & 15) << 2;
        float4 v = *(const float4*)&in[(size_t)(rt + r) * C + ct + c];
        tile[r][c] = v.x; tile[r][c + 1] = v.y; tile[r][c + 2] = v.z; tile[r][c + 3] = v.w;
    }
    __syncthreads();
#pragma unroll
    for (int i = 0; i < 4; ++i) {
        int fid = i * 256 + t;
        int c = fid >> 4;
        int r0 = (fid & 15) << 2;
        ushort4 o;
        o.x = f2bf(tile[r0][c]);     o.y = f2bf(tile[r0 + 1][c]);
        o.z = f2bf(tile[r0 + 2][c]); o.w = f2bf(tile[r0 + 3][c]);
        *(ushort4*)&out[(size_t)(ct + c) * R + rt + r0] = o;
    }
}

// ======== GEMM1: 256x256 tile, BK=64, 8-phase counted-vmcnt, 16 WAVES ========
// Round-5 lesson: with 8 waves the allocator pins 128 VGPR and spills the
// 128-reg accumulator (43MB scratch). 16 waves -> per-wave tile 64x64 ->
// acc[4][4]=64 VGPR + 32 frag -> ~115 total, fits the 128 cap BY CONSTRUCTION.
// 4 waves/SIMD also doubles latency hiding. Same swizzle (rule #21) + T5.
__global__ __launch_bounds__(1024) void k_gemm1(
    const unsigned short* __restrict__ A,
    const unsigned short* __restrict__ Bt,
    const float* __restrict__ bias,
    unsigned short* __restrict__ out_qk,
    unsigned short* __restrict__ out_vT)
{
    __shared__ __align__(16) char smem[131072];  // [A 2x32KB][B 2x32KB]
    const int t = threadIdx.x;
    const int wave = t >> 6, lane = t & 63;
    const int lr = lane & 15, lg = lane >> 4;
    const int wr = wave >> 2, wc = wave & 3;     // 4M x 4N wave grid

    // XCD swizzle: 384 blocks -> 48 contiguous per XCD (A-panel locality)
    const int lid = blockIdx.x;
    const int swz = (lid & 7) * 48 + (lid >> 3);
    const int tile_m = (swz / 12) * 256;
    const int tile_n = (swz % 12) * 256;

    const int srow = lane >> 3;                  // row within wave's 8-row slab
    const int sblk = (lane & 7) ^ srow;          // inverse-swizzled 16B block

    f32x4 acc[4][4];
#pragma unroll
    for (int i = 0; i < 4; ++i)
#pragma unroll
        for (int j = 0; j < 4; ++j)
            acc[i][j] = (f32x4){0.f, 0.f, 0.f, 0.f};

    // stage half-pair h of K-tile kt into buffer buf: 1 A + 1 B load/thread.
    // LDS layout per region: [256 rows][128B] row-major; LDS block j of row r
    // holds global 16B-block j^(r&7)  (involution; read applies same XOR).
    auto stage2 = [&](int kt, int buf, int h) {
        const int r = wave * 8 + srow;           // 0..127 within half
        const int dst = buf * 32768 + h * 16384 + wave * 1024 + lane * 16;
        gload_lds16(&A[(size_t)(tile_m + h * 128 + r) * 1024 + kt * 64 + sblk * 8],
                    smem + dst);
        gload_lds16(&Bt[(size_t)(tile_n + h * 128 + r) * 1024 + kt * 64 + sblk * 8],
                    smem + 65536 + dst);
    };

    // prologue: K-tile 0 -> buf0
    stage2(0, 0, 0);
    stage2(0, 0, 1);
    VMCNT(0);
    SB(); __builtin_amdgcn_s_barrier(); SB();

    bf16x8 af[2][2], bf[2][2];

    for (int tt = 0; tt < 8; ++tt) {
#pragma unroll
        for (int p = 0; p < 8; ++p) {
            const int b = p >> 2, q = p & 3;     // buffer, quadrant
            const int mh = q >> 1, nh = q & 1;
            const int abase = b * 32768;
            const int bbase = 65536 + b * 32768;
            // --- 1. ds_read this quadrant's fragments ---
#pragma unroll
            for (int mi = 0; mi < 2; ++mi) {
                const int row = wr * 64 + mh * 32 + mi * 16 + lr;
#pragma unroll
                for (int kk = 0; kk < 2; ++kk)
                    af[mi][kk] = *(const bf16x8*)(smem + abase + row * 128 +
                                    (((kk * 4 + lg) ^ (row & 7)) << 4));
            }
#pragma unroll
            for (int ni = 0; ni < 2; ++ni) {
                const int row = wc * 64 + nh * 32 + ni * 16 + lr;
#pragma unroll
                for (int kk = 0; kk < 2; ++kk)
                    bf[ni][kk] = *(const bf16x8*)(smem + bbase + row * 128 +
                                    (((kk * 4 + lg) ^ (row & 7)) << 4));
            }
            // --- 2. prefetch: buf1<-kt(2tt+1) at p0/p1, buf0<-kt(2tt+2) at p4/p5 ---
            if (p == 0) stage2(2 * tt + 1, 1, 0);
            if (p == 1) stage2(2 * tt + 1, 1, 1);
            if (p == 4 && tt < 7) stage2(2 * tt + 2, 0, 0);
            if (p == 5 && tt < 7) stage2(2 * tt + 2, 0, 1);

            SB(); __builtin_amdgcn_s_barrier(); SB();

            // --- 3. MFMA: quadrant (mh,nh) x K=64 = 8 MFMA ---
            __builtin_amdgcn_s_setprio(1);
#pragma unroll
            for (int kk = 0; kk < 2; ++kk)
#pragma unroll
                for (int mi = 0; mi < 2; ++mi)
#pragma unroll
                    for (int ni = 0; ni < 2; ++ni)
                        acc[mh * 2 + mi][nh * 2 + ni] = __builtin_amdgcn_mfma_f32_16x16x32_bf16(
                            af[mi][kk], bf[ni][kk], acc[mh * 2 + mi][nh * 2 + ni], 0, 0, 0);
            __builtin_amdgcn_s_setprio(0);

            // --- 4. buffer boundary: next buffer's refill must have landed ---
            if (q == 3) { VMCNT(0); }
            SB(); __builtin_amdgcn_s_barrier(); SB();
        }
    }

    // ---- epilogue: D row(m) = lg*4+reg, col(n) = lr ----
#pragma unroll
    for (int J = 0; J < 4; ++J) {
        const int n = tile_n + wc * 64 + (J >> 1) * 32 + (J & 1) * 16 + lr;
        const float bv = bias[n];
#pragma unroll
        for (int I = 0; I < 4; ++I) {
            const int m0 = tile_m + wr * 64 + (I >> 1) * 32 + (I & 1) * 16 + lg * 4;
            f32x4 v = acc[I][J];
            if (n < 2048) {          // Q,K region: row-major [m][2048]
#pragma unroll
                for (int r = 0; r < 4; ++r)
                    out_qk[(size_t)(m0 + r) * 2048 + n] = f2bf(v[r] + bv);
            } else {                 // V region: transposed [head][d][x]
                int hd = (n - 2048) >> 7;
                int dd = (n - 2048) & 127;
                int bn = m0 >> 10;
                int x0 = m0 & 1023;
                ushort4 o;
                o.x = f2bf(v[0] + bv); o.y = f2bf(v[1] + bv);
                o.z = f2bf(v[2] + bv); o.w = f2bf(v[3] + bv);
                *(ushort4*)&out_vT[((size_t)(bn * 8 + hd) * 128 + dd) * 1024 + x0] = o;
            }
        }
    }
}

// ---------------- GEMM2 (m97-style 128^2): out = ctx*w_outT + bias + resid ----------------
__global__ __launch_bounds__(256, 2) void k_gemm2(
    const unsigned short* __restrict__ A,
    const unsigned short* __restrict__ Bt,
    const float* __restrict__ bias,
    const float* __restrict__ resid,
    float* __restrict__ out_f,
    int Kdim)
{
    __shared__ __align__(16) unsigned short Al[128 * 64];
    __shared__ __align__(16) unsigned short Bl[128 * 64];
    const int t = threadIdx.x;
    const int wave = t >> 6, lane = t & 63;
    const int wm = wave >> 1, wn = wave & 1;
    const int lr = lane & 15, lg = lane >> 4;
    const int tile_m = blockIdx.y * 128;
    const int tile_n = blockIdx.x * 128;

    f32x4 acc[4][4];
#pragma unroll
    for (int i = 0; i < 4; ++i)
#pragma unroll
        for (int j = 0; j < 4; ++j)
            acc[i][j] = (f32x4){0.f, 0.f, 0.f, 0.f};

    const int srow = lane >> 3;
    const int scol = (lane & 7) * 8;

    for (int kt = 0; kt < Kdim; kt += 64) {
#pragma unroll
        for (int i = 0; i < 4; ++i) {
            int chunk = i * 4 + wave;
            int row = chunk * 8 + srow;
            gload_lds16(&A[(size_t)(tile_m + row) * Kdim + kt + scol], &Al[chunk * 512]);
            gload_lds16(&Bt[(size_t)(tile_n + row) * Kdim + kt + scol], &Bl[chunk * 512]);
        }
        __syncthreads();
#pragma unroll
        for (int kk = 0; kk < 2; ++kk) {
            bf16x8 af[4], bfr[4];
#pragma unroll
            for (int mi = 0; mi < 4; ++mi)
                af[mi] = *(const bf16x8*)&Al[(wm * 64 + mi * 16 + lr) * 64 + kk * 32 + lg * 8];
#pragma unroll
            for (int ni = 0; ni < 4; ++ni)
                bfr[ni] = *(const bf16x8*)&Bl[(wn * 64 + ni * 16 + lr) * 64 + kk * 32 + lg * 8];
#pragma unroll
            for (int mi = 0; mi < 4; ++mi)
#pragma unroll
                for (int ni = 0; ni < 4; ++ni)
                    acc[mi][ni] = __builtin_amdgcn_mfma_f32_16x16x32_bf16(af[mi], bfr[ni], acc[mi][ni], 0, 0, 0);
        }
        __syncthreads();
    }

#pragma unroll
    for (int ni = 0; ni < 4; ++ni) {
        int n = tile_n + wn * 64 + ni * 16 + lr;
        float bv = bias[n];
#pragma unroll
        for (int mi = 0; mi < 4; ++mi) {
            int m0 = tile_m + wm * 64 + mi * 16 + lg * 4;
            f32x4 v = acc[mi][ni];
#pragma unroll
            for (int r = 0; r < 4; ++r) {
                size_t idx = (size_t)(m0 + r) * 1024 + n;
                out_f[idx] = v[r] + bv + resid[idx];
            }
        }
    }
}

// ---------------- flash attention (v3: gload_lds dbuf, counted vmcnt) ----------------
__global__ __launch_bounds__(256, 2) void k_attn(
    const unsigned short* __restrict__ qk,   // [8192][2048] bf16 (Q | K)
    const unsigned short* __restrict__ vT,   // [64 heads][128 d][1024 x] bf16
    unsigned short* __restrict__ ctx)        // [8192][1024] bf16
{
    __shared__ __align__(16) unsigned short Kl[2 * 64 * 128];
    __shared__ __align__(16) unsigned short Vl[2 * 128 * 64];
    __shared__ __align__(16) unsigned short Pl[128 * 64];
    const int t = threadIdx.x;
    const int wave = t >> 6, lane = t & 63;
    const int lr = lane & 15, lg = lane >> 4;

    const int lid = blockIdx.y * gridDim.x + blockIdx.x;
    const int xcd = lid & 7, slot = lid >> 3;
    const int head = xcd * 8 + (slot & 7);
    const int qblk = slot >> 3;

    const int h = head & 7;
    const int tok0 = (head >> 3) * 1024;
    const int qtok = tok0 + qblk * 128 + wave * 32;
    const float cl2 = 0.08838834764831845f * 1.44269504088896f;

    const unsigned short* kbase = &qk[(size_t)tok0 * 2048 + 1024 + h * 128];
    const unsigned short* vhead = &vT[(size_t)head * 128 * 1024];

    auto stage = [&](int x0, int buf) {
        unsigned short* Kb = (unsigned short*)((char*)Kl + buf * 16384);
        unsigned short* Vb = (unsigned short*)((char*)Vl + buf * 16384);
#pragma unroll
        for (int i = 0; i < 4; ++i) {
            int x = i * 16 + wave * 4 + (lane >> 4);
            int ck = (lane & 15) ^ (x & 7);
            gload_lds16(&kbase[(size_t)(x0 + x) * 2048 + ck * 8], &Kb[i * 2048 + wave * 512]);
            int d = i * 32 + wave * 8 + (lane >> 3);
            int cv = (lane & 7) ^ (d & 7);
            gload_lds16(&vhead[(size_t)d * 1024 + x0 + cv * 8], &Vb[i * 2048 + wave * 512]);
        }
    };

    bf16x8 qf[2][4];
#pragma unroll
    for (int nq = 0; nq < 2; ++nq)
#pragma unroll
        for (int kk = 0; kk < 4; ++kk)
            qf[nq][kk] = *(const bf16x8*)&qk[(size_t)(qtok + 16 * nq + lr) * 2048 + h * 128 + kk * 32 + lg * 8];

    f32x4 o[2][8];
#pragma unroll
    for (int a = 0; a < 2; ++a)
#pragma unroll
        for (int b = 0; b < 8; ++b)
            o[a][b] = (f32x4){0.f, 0.f, 0.f, 0.f};
    float m_run[2] = {-3.0e38f, -3.0e38f};
    float l_run[2] = {0.f, 0.f};

    stage(0, 0);

    for (int tile = 0; tile < 16; ++tile) {
        const int kb = (tile & 1) * 16384;
        if (tile < 15) {
            stage((tile + 1) * 64, (tile + 1) & 1);
            VMCNT(8);
        } else {
            VMCNT(0);
        }
        SB(); __builtin_amdgcn_s_barrier(); SB();

        f32x4 s[4][2];
#pragma unroll
        for (int mi = 0; mi < 4; ++mi)
#pragma unroll
            for (int nq = 0; nq < 2; ++nq)
                s[mi][nq] = (f32x4){0.f, 0.f, 0.f, 0.f};
#pragma unroll
        for (int kk = 0; kk < 4; ++kk) {
            bf16x8 kf[4];
#pragma unroll
            for (int mi = 0; mi < 4; ++mi) {
                int row = mi * 16 + lr;
                int byte = (row * 256 + kk * 64 + lg * 16) ^ ((row & 7) << 4);
                kf[mi] = *(const bf16x8*)((const char*)Kl + kb + byte);
            }
            __builtin_amdgcn_s_setprio(1);
#pragma unroll
            for (int mi = 0; mi < 4; ++mi)
#pragma unroll
                for (int nq = 0; nq < 2; ++nq)
                    s[mi][nq] = __builtin_amdgcn_mfma_f32_16x16x32_bf16(kf[mi], qf[nq][kk], s[mi][nq], 0, 0, 0);
            __builtin_amdgcn_s_setprio(0);
        }

        float fac[2];
        bool doresc[2];
#pragma unroll
        for (int nq = 0; nq < 2; ++nq) {
            float mx = -3.0e38f;
#pragma unroll
            for (int mi = 0; mi < 4; ++mi)
#pragma unroll
                for (int r = 0; r < 4; ++r)
                    mx = fmaxf(mx, s[mi][nq][r]);
            mx = fmaxf(mx, __shfl_xor(mx, 16));
            mx = fmaxf(mx, __shfl_xor(mx, 32));
            float mxl = mx * cl2;
            float mr = m_run[nq];
            if (__any(mxl - mr > 8.0f)) {
                float mn = fmaxf(mr, mxl);
                fac[nq] = __builtin_amdgcn_exp2f(mr - mn);
                m_run[nq] = mn;
                doresc[nq] = true;
            } else {
                fac[nq] = 1.0f;
                doresc[nq] = false;
            }
            const float nmn = -m_run[nq];
            float sum = 0.f;
            const int q = wave * 32 + nq * 16 + lr;
#pragma unroll
            for (int mi = 0; mi < 4; ++mi) {
                float p0 = __builtin_amdgcn_exp2f(__builtin_fmaf(s[mi][nq][0], cl2, nmn));
                float p1 = __builtin_amdgcn_exp2f(__builtin_fmaf(s[mi][nq][1], cl2, nmn));
                float p2 = __builtin_amdgcn_exp2f(__builtin_fmaf(s[mi][nq][2], cl2, nmn));
                float p3 = __builtin_amdgcn_exp2f(__builtin_fmaf(s[mi][nq][3], cl2, nmn));
                sum += (p0 + p1) + (p2 + p3);
                uint2 pk;
                pk.x = cvt_pk_bf16(p0, p1);
                pk.y = cvt_pk_bf16(p2, p3);
                int byte = (q * 128 + (mi * 16 + lg * 4) * 2) ^ ((q & 7) << 4);
                *(uint2*)((char*)Pl + byte) = pk;
            }
            sum += __shfl_xor(sum, 16);
            sum += __shfl_xor(sum, 32);
            l_run[nq] = l_run[nq] * fac[nq] + sum;
        }

#pragma unroll
        for (int mo = 0; mo < 2; ++mo)
            if (doresc[mo]) {
#pragma unroll
                for (int r = 0; r < 4; ++r) {
                    int src = (lane & 48) | (lg * 4 + r);
                    float f = __shfl(fac[mo], src);
#pragma unroll
                    for (int nd = 0; nd < 8; ++nd)
                        o[mo][nd][r] *= f;
                }
            }

#pragma unroll
        for (int kk = 0; kk < 2; ++kk) {
            bf16x8 pf[2], vf[8];
#pragma unroll
            for (int mo = 0; mo < 2; ++mo) {
                int q = wave * 32 + mo * 16 + lr;
                int byte = (q * 128 + kk * 64 + lg * 16) ^ ((q & 7) << 4);
                pf[mo] = *(const bf16x8*)((const char*)Pl + byte);
            }
#pragma unroll
            for (int nd = 0; nd < 8; ++nd) {
                int drow = nd * 16 + lr;
                int byte = (drow * 128 + kk * 64 + lg * 16) ^ ((drow & 7) << 4);
                vf[nd] = *(const bf16x8*)((const char*)Vl + kb + byte);
            }
            __builtin_amdgcn_s_setprio(1);
#pragma unroll
            for (int mo = 0; mo < 2; ++mo)
#pragma unroll
                for (int nd = 0; nd < 8; ++nd)
                    o[mo][nd] = __builtin_amdgcn_mfma_f32_16x16x32_bf16(pf[mo], vf[nd], o[mo][nd], 0, 0, 0);
            __builtin_amdgcn_s_setprio(0);
        }
        __builtin_amdgcn_s_barrier(); SB();
    }

#pragma unroll
    for (int mo = 0; mo < 2; ++mo) {
        float rl[4];
#pragma unroll
        for (int r = 0; r < 4; ++r) {
            int src = (lane & 48) | (lg * 4 + r);
            rl[r] = 1.0f / __shfl(l_run[mo], src);
        }
#pragma unroll
        for (int nd = 0; nd < 8; ++nd)
#pragma unroll
            for (int r = 0; r < 4; ++r) {
                int q = qtok + mo * 16 + lg * 4 + r;
                ctx[(size_t)q * 1024 + h * 128 + nd * 16 + lr] = f2bf(o[mo][nd][r] * rl[r]);
            }
    }
}

// ---------------- in-place LayerNorm over D=1024 ----------------
__global__ __launch_bounds__(256) void k_ln(float* __restrict__ io,
                                            const float* __restrict__ gamma,
                                            const float* __restrict__ beta)
{
    __shared__ float bs[4], bss[4];
    const int row = blockIdx.x;
    const int t = threadIdx.x;
    float4 v = ((const float4*)&io[(size_t)row * 1024])[t];
    float s = (v.x + v.y) + (v.z + v.w);
    float ss = (v.x * v.x + v.y * v.y) + (v.z * v.z + v.w * v.w);
#pragma unroll
    for (int off = 32; off >= 1; off >>= 1) {
        s += __shfl_xor(s, off);
        ss += __shfl_xor(ss, off);
    }
    if ((t & 63) == 0) { bs[t >> 6] = s; bss[t >> 6] = ss; }
    __syncthreads();
    s = (bs[0] + bs[1]) + (bs[2] + bs[3]);
    ss = (bss[0] + bss[1]) + (bss[2] + bss[3]);
    const float mu = s * (1.f / 1024.f);
    const float var = ss * (1.f / 1024.f) - mu * mu;
    const float rs = rsqrtf(var + 1e-5f);
    float4 g = ((const float4*)gamma)[t];
    float4 b = ((const float4*)beta)[t];
    float4 ov;
    ov.x = (v.x - mu) * rs * g.x + b.x;
    ov.y = (v.y - mu) * rs * g.y + b.y;
    ov.z = (v.z - mu) * rs * g.z + b.z;
    ov.w = (v.w - mu) * rs * g.w + b.w;
    ((float4*)&io[(size_t)row * 1024])[t] = ov;
}

extern "C" void kernel_launch(void* const* d_in, const int* in_sizes, int n_in,
                              void* d_out, int out_size, void* d_ws, size_t ws_size,
                              hipStream_t stream)
{
    const float* val   = (const float*)d_in[0];
    const float* w_qkv = (const float*)d_in[1];
    const float* b_qkv = (const float*)d_in[2];
    const float* w_out = (const float*)d_in[3];
    const float* b_out = (const float*)d_in[4];
    const float* ln_g  = (const float*)d_in[5];
    const float* ln_b  = (const float*)d_in[6];
    float* out = (float*)d_out;

    char* ws = (char*)d_ws;
    unsigned short* qk     = (unsigned short*)(ws + 0);          // 33,554,432 B
    unsigned short* vTb    = (unsigned short*)(ws + 33554432);   // 16,777,216 B
    unsigned short* ctx    = (unsigned short*)(ws + 50331648);   // 16,777,216 B
    unsigned short* w_outT = (unsigned short*)(ws + 67108864);   //  2,097,152 B
    unsigned short* w_qkvT = (unsigned short*)(ws + 69206016);   //  6,291,456 B
    unsigned short* valb   = (unsigned short*)(ws + 75497472);   // 16,777,216 B

    k_convert<<<8192, 256, 0, stream>>>(val, valb, 2097152);
    k_transpose<<<dim3(48, 16), 256, 0, stream>>>(w_qkv, w_qkvT, 1024, 3072);
    k_transpose<<<dim3(16, 16), 256, 0, stream>>>(w_out, w_outT, 1024, 1024);
    k_gemm1<<<384, 1024, 0, stream>>>(valb, w_qkvT, b_qkv, qk, vTb);
    k_attn<<<dim3(8, 64), 256, 0, stream>>>(qk, vTb, ctx);
    k_gemm2<<<dim3(8, 64), 256, 0, stream>>>(ctx, w_outT, b_out, val, out, 1024);
    k_ln<<<8192, 256, 0, stream>>>(out, ln_g, ln_b);
}

// Round 7
// 172.993 us; speedup vs baseline: 1.2733x; 1.2733x over previous
//
#include <hip/hip_runtime.h>
#include <hip/hip_bf16.h>
#include <stdint.h>

// Problem: B=2, S=4096, D=1024, H=8, DH=128, W=1024, nb=4, M=B*S=8192
// Pipeline: convert/transpose -> GEMM1 (256x128 8-phase, 8 waves, qkv -> Q/K + V^T)
//           -> flash attention (counted-vmcnt dbuf) -> GEMM2 (+bias+residual)
//           -> in-place LayerNorm.

typedef float f32x4 __attribute__((ext_vector_type(4)));
typedef __bf16 bf16x8 __attribute__((ext_vector_type(8)));

static __device__ __forceinline__ unsigned short f2bf(float f) {
    unsigned int u = __builtin_bit_cast(unsigned int, f);
    u += 0x7fffu + ((u >> 16) & 1u);
    return (unsigned short)(u >> 16);
}

static __device__ __forceinline__ unsigned cvt_pk_bf16(float lo, float hi) {
    unsigned r;
    asm("v_cvt_pk_bf16_f32 %0, %1, %2" : "=v"(r) : "v"(lo), "v"(hi));
    return r;
}

static __device__ __forceinline__ void gload_lds16(const void* g, void* l) {
    __builtin_amdgcn_global_load_lds(
        (__attribute__((address_space(1))) void*)(g),
        (__attribute__((address_space(3))) void*)(l), 16, 0, 0);
}

#define VMCNT(n) asm volatile("s_waitcnt vmcnt(" #n ")" ::: "memory")
#define SB() __builtin_amdgcn_sched_barrier(0)

// ---------------- convert f32 -> bf16 ----------------
__global__ __launch_bounds__(256) void k_convert(const float* __restrict__ in,
                                                 unsigned short* __restrict__ out,
                                                 int n4) {
    int i = blockIdx.x * 256 + threadIdx.x;
    if (i >= n4) return;
    float4 v = ((const float4*)in)[i];
    ushort4 o;
    o.x = f2bf(v.x); o.y = f2bf(v.y); o.z = f2bf(v.z); o.w = f2bf(v.w);
    ((ushort4*)out)[i] = o;
}

// ---------------- transpose f32 [R][C] -> bf16 [C][R] ----------------
__global__ __launch_bounds__(256) void k_transpose(const float* __restrict__ in,
                                                   unsigned short* __restrict__ out,
                                                   int R, int C) {
    __shared__ float tile[64][65];
    const int rt = blockIdx.y * 64, ct = blockIdx.x * 64;
    const int t = threadIdx.x;
#pragma unroll
    for (int i = 0; i < 4; ++i) {
        int fid = i * 256 + t;
        int r = fid >> 4;
        int c = (fid & 15) << 2;
        float4 v = *(const float4*)&in[(size_t)(rt + r) * C + ct + c];
        tile[r][c] = v.x; tile[r][c + 1] = v.y; tile[r][c + 2] = v.z; tile[r][c + 3] = v.w;
    }
    __syncthreads();
#pragma unroll
    for (int i = 0; i < 4; ++i) {
        int fid = i * 256 + t;
        int c = fid >> 4;
        int r0 = (fid & 15) << 2;
        ushort4 o;
        o.x = f2bf(tile[r0][c]);     o.y = f2bf(tile[r0 + 1][c]);
        o.z = f2bf(tile[r0 + 2][c]); o.w = f2bf(tile[r0 + 3][c]);
        *(ushort4*)&out[(size_t)(ct + c) * R + rt + r0] = o;
    }
}

// ======== GEMM1: 256x128 tile, BK=64, 8-phase counted-vmcnt, 8 waves ========
// Round-4/5/6 lesson: allocator caps VGPR at 128 for 512-thread blocks (64 for
// 1024-thread) regardless of launch_bounds; fit under 128 BY CONSTRUCTION:
// 8 waves (4M x 2N), per-wave 64x64 -> acc[4][4]=64 + frags 32 + addr ~20 = ~116.
// LDS 96KB dbuf (A 2x32KB, B 2x16KB). Swizzle rule #21 both-sides. T5 setprio.
__global__ __launch_bounds__(512) void k_gemm1(
    const unsigned short* __restrict__ A,
    const unsigned short* __restrict__ Bt,
    const float* __restrict__ bias,
    unsigned short* __restrict__ out_qk,
    unsigned short* __restrict__ out_vT)
{
    __shared__ __align__(16) char smem[98304];   // A: 2x32KB @0, B: 2x16KB @65536
    const int t = threadIdx.x;
    const int wave = t >> 6, lane = t & 63;
    const int lr = lane & 15, lg = lane >> 4;
    const int wr = wave >> 1, wc = wave & 1;     // 4M x 2N wave grid

    // grid 768 = 32 Mtiles x 24 Ntiles; XCD gets 96 contiguous (m-major groups;
    // cross-XCD B re-reads are L3-served)
    const int lid = blockIdx.x;
    const int swz = (lid & 7) * 96 + (lid >> 3);
    const int tile_m = (swz / 24) * 256;
    const int tile_n = (swz % 24) * 128;

    const int srow = lane >> 3;                  // row within 8-row slab
    const int sblk = (lane & 7) ^ srow;          // inverse-swizzled 16B block

    f32x4 acc[4][4];
#pragma unroll
    for (int i = 0; i < 4; ++i)
#pragma unroll
        for (int j = 0; j < 4; ++j)
            acc[i][j] = (f32x4){0.f, 0.f, 0.f, 0.f};

    // stage half h of K-tile kt into buffer buf: 2 A-loads + 1 B-load /thread.
    // LDS region layout: [rows][128B] row-major; block j of row r holds global
    // block j^(r&7) (involution; ds_read applies the same XOR).
    auto stage2 = [&](int kt, int buf, int h) {
#pragma unroll
        for (int i = 0; i < 2; ++i) {
            int r = h * 128 + i * 64 + wave * 8 + srow;
            int dst = buf * 32768 + h * 16384 + i * 8192 + wave * 1024 + lane * 16;
            gload_lds16(&A[(size_t)(tile_m + r) * 1024 + kt * 64 + sblk * 8], smem + dst);
        }
        int rb = h * 64 + wave * 8 + srow;
        int dstb = 65536 + buf * 16384 + h * 8192 + wave * 1024 + lane * 16;
        gload_lds16(&Bt[(size_t)(tile_n + rb) * 1024 + kt * 64 + sblk * 8], smem + dstb);
    };

    // prologue: K-tile 0 -> buf0
    stage2(0, 0, 0);
    stage2(0, 0, 1);
    VMCNT(0);
    SB(); __builtin_amdgcn_s_barrier(); SB();

    bf16x8 af[2][2], bf[2][2];

    for (int tt = 0; tt < 8; ++tt) {
#pragma unroll
        for (int p = 0; p < 8; ++p) {
            const int b = p >> 2, q = p & 3;     // buffer, quadrant
            const int mh = q >> 1, nh = q & 1;
            const int abase = b * 32768;
            const int bbase = 65536 + b * 16384;
            // --- 1. ds_read this quadrant's fragments ---
#pragma unroll
            for (int mi = 0; mi < 2; ++mi) {
                const int row = wr * 64 + mh * 32 + mi * 16 + lr;
#pragma unroll
                for (int kk = 0; kk < 2; ++kk)
                    af[mi][kk] = *(const bf16x8*)(smem + abase + row * 128 +
                                    (((kk * 4 + lg) ^ (row & 7)) << 4));
            }
#pragma unroll
            for (int ni = 0; ni < 2; ++ni) {
                const int row = wc * 64 + nh * 32 + ni * 16 + lr;
#pragma unroll
                for (int kk = 0; kk < 2; ++kk)
                    bf[ni][kk] = *(const bf16x8*)(smem + bbase + row * 128 +
                                    (((kk * 4 + lg) ^ (row & 7)) << 4));
            }
            // --- 2. prefetch: buf1<-kt(2tt+1) at p0/p1, buf0<-kt(2tt+2) at p4/p5 ---
            if (p == 0) stage2(2 * tt + 1, 1, 0);
            if (p == 1) stage2(2 * tt + 1, 1, 1);
            if (p == 4 && tt < 7) stage2(2 * tt + 2, 0, 0);
            if (p == 5 && tt < 7) stage2(2 * tt + 2, 0, 1);

            SB(); __builtin_amdgcn_s_barrier(); SB();

            // --- 3. MFMA: quadrant (mh,nh) x K=64 = 8 MFMA ---
            __builtin_amdgcn_s_setprio(1);
#pragma unroll
            for (int kk = 0; kk < 2; ++kk)
#pragma unroll
                for (int mi = 0; mi < 2; ++mi)
#pragma unroll
                    for (int ni = 0; ni < 2; ++ni)
                        acc[mh * 2 + mi][nh * 2 + ni] = __builtin_amdgcn_mfma_f32_16x16x32_bf16(
                            af[mi][kk], bf[ni][kk], acc[mh * 2 + mi][nh * 2 + ni], 0, 0, 0);
            __builtin_amdgcn_s_setprio(0);

            // --- 4. buffer boundary: next buffer's refill must have landed ---
            if (q == 3) { VMCNT(0); }
            SB(); __builtin_amdgcn_s_barrier(); SB();
        }
    }

    // ---- epilogue: D row(m) = lg*4+reg, col(n) = lr ----
#pragma unroll
    for (int J = 0; J < 4; ++J) {
        const int n = tile_n + wc * 64 + (J >> 1) * 32 + (J & 1) * 16 + lr;
        const float bv = bias[n];
#pragma unroll
        for (int I = 0; I < 4; ++I) {
            const int m0 = tile_m + wr * 64 + (I >> 1) * 32 + (I & 1) * 16 + lg * 4;
            f32x4 v = acc[I][J];
            if (n < 2048) {          // Q,K region: row-major [m][2048]
#pragma unroll
                for (int r = 0; r < 4; ++r)
                    out_qk[(size_t)(m0 + r) * 2048 + n] = f2bf(v[r] + bv);
            } else {                 // V region: transposed [head][d][x]
                int hd = (n - 2048) >> 7;
                int dd = (n - 2048) & 127;
                int bn = m0 >> 10;
                int x0 = m0 & 1023;
                ushort4 o;
                o.x = f2bf(v[0] + bv); o.y = f2bf(v[1] + bv);
                o.z = f2bf(v[2] + bv); o.w = f2bf(v[3] + bv);
                *(ushort4*)&out_vT[((size_t)(bn * 8 + hd) * 128 + dd) * 1024 + x0] = o;
            }
        }
    }
}

// ---------------- GEMM2 (m97-style 128^2): out = ctx*w_outT + bias + resid ----------------
__global__ __launch_bounds__(256, 2) void k_gemm2(
    const unsigned short* __restrict__ A,
    const unsigned short* __restrict__ Bt,
    const float* __restrict__ bias,
    const float* __restrict__ resid,
    float* __restrict__ out_f,
    int Kdim)
{
    __shared__ __align__(16) unsigned short Al[128 * 64];
    __shared__ __align__(16) unsigned short Bl[128 * 64];
    const int t = threadIdx.x;
    const int wave = t >> 6, lane = t & 63;
    const int wm = wave >> 1, wn = wave & 1;
    const int lr = lane & 15, lg = lane >> 4;
    const int tile_m = blockIdx.y * 128;
    const int tile_n = blockIdx.x * 128;

    f32x4 acc[4][4];
#pragma unroll
    for (int i = 0; i < 4; ++i)
#pragma unroll
        for (int j = 0; j < 4; ++j)
            acc[i][j] = (f32x4){0.f, 0.f, 0.f, 0.f};

    const int srow = lane >> 3;
    const int scol = (lane & 7) * 8;

    for (int kt = 0; kt < Kdim; kt += 64) {
#pragma unroll
        for (int i = 0; i < 4; ++i) {
            int chunk = i * 4 + wave;
            int row = chunk * 8 + srow;
            gload_lds16(&A[(size_t)(tile_m + row) * Kdim + kt + scol], &Al[chunk * 512]);
            gload_lds16(&Bt[(size_t)(tile_n + row) * Kdim + kt + scol], &Bl[chunk * 512]);
        }
        __syncthreads();
#pragma unroll
        for (int kk = 0; kk < 2; ++kk) {
            bf16x8 af[4], bfr[4];
#pragma unroll
            for (int mi = 0; mi < 4; ++mi)
                af[mi] = *(const bf16x8*)&Al[(wm * 64 + mi * 16 + lr) * 64 + kk * 32 + lg * 8];
#pragma unroll
            for (int ni = 0; ni < 4; ++ni)
                bfr[ni] = *(const bf16x8*)&Bl[(wn * 64 + ni * 16 + lr) * 64 + kk * 32 + lg * 8];
#pragma unroll
            for (int mi = 0; mi < 4; ++mi)
#pragma unroll
                for (int ni = 0; ni < 4; ++ni)
                    acc[mi][ni] = __builtin_amdgcn_mfma_f32_16x16x32_bf16(af[mi], bfr[ni], acc[mi][ni], 0, 0, 0);
        }
        __syncthreads();
    }

#pragma unroll
    for (int ni = 0; ni < 4; ++ni) {
        int n = tile_n + wn * 64 + ni * 16 + lr;
        float bv = bias[n];
#pragma unroll
        for (int mi = 0; mi < 4; ++mi) {
            int m0 = tile_m + wm * 64 + mi * 16 + lg * 4;
            f32x4 v = acc[mi][ni];
#pragma unroll
            for (int r = 0; r < 4; ++r) {
                size_t idx = (size_t)(m0 + r) * 1024 + n;
                out_f[idx] = v[r] + bv + resid[idx];
            }
        }
    }
}

// ---------------- flash attention (v3: gload_lds dbuf, counted vmcnt) ----------------
__global__ __launch_bounds__(256, 2) void k_attn(
    const unsigned short* __restrict__ qk,   // [8192][2048] bf16 (Q | K)
    const unsigned short* __restrict__ vT,   // [64 heads][128 d][1024 x] bf16
    unsigned short* __restrict__ ctx)        // [8192][1024] bf16
{
    __shared__ __align__(16) unsigned short Kl[2 * 64 * 128];
    __shared__ __align__(16) unsigned short Vl[2 * 128 * 64];
    __shared__ __align__(16) unsigned short Pl[128 * 64];
    const int t = threadIdx.x;
    const int wave = t >> 6, lane = t & 63;
    const int lr = lane & 15, lg = lane >> 4;

    const int lid = blockIdx.y * gridDim.x + blockIdx.x;
    const int xcd = lid & 7, slot = lid >> 3;
    const int head = xcd * 8 + (slot & 7);
    const int qblk = slot >> 3;

    const int h = head & 7;
    const int tok0 = (head >> 3) * 1024;
    const int qtok = tok0 + qblk * 128 + wave * 32;
    const float cl2 = 0.08838834764831845f * 1.44269504088896f;

    const unsigned short* kbase = &qk[(size_t)tok0 * 2048 + 1024 + h * 128];
    const unsigned short* vhead = &vT[(size_t)head * 128 * 1024];

    auto stage = [&](int x0, int buf) {
        unsigned short* Kb = (unsigned short*)((char*)Kl + buf * 16384);
        unsigned short* Vb = (unsigned short*)((char*)Vl + buf * 16384);
#pragma unroll
        for (int i = 0; i < 4; ++i) {
            int x = i * 16 + wave * 4 + (lane >> 4);
            int ck = (lane & 15) ^ (x & 7);
            gload_lds16(&kbase[(size_t)(x0 + x) * 2048 + ck * 8], &Kb[i * 2048 + wave * 512]);
            int d = i * 32 + wave * 8 + (lane >> 3);
            int cv = (lane & 7) ^ (d & 7);
            gload_lds16(&vhead[(size_t)d * 1024 + x0 + cv * 8], &Vb[i * 2048 + wave * 512]);
        }
    };

    bf16x8 qf[2][4];
#pragma unroll
    for (int nq = 0; nq < 2; ++nq)
#pragma unroll
        for (int kk = 0; kk < 4; ++kk)
            qf[nq][kk] = *(const bf16x8*)&qk[(size_t)(qtok + 16 * nq + lr) * 2048 + h * 128 + kk * 32 + lg * 8];

    f32x4 o[2][8];
#pragma unroll
    for (int a = 0; a < 2; ++a)
#pragma unroll
        for (int b = 0; b < 8; ++b)
            o[a][b] = (f32x4){0.f, 0.f, 0.f, 0.f};
    float m_run[2] = {-3.0e38f, -3.0e38f};
    float l_run[2] = {0.f, 0.f};

    stage(0, 0);

    for (int tile = 0; tile < 16; ++tile) {
        const int kb = (tile & 1) * 16384;
        if (tile < 15) {
            stage((tile + 1) * 64, (tile + 1) & 1);
            VMCNT(8);
        } else {
            VMCNT(0);
        }
        SB(); __builtin_amdgcn_s_barrier(); SB();

        f32x4 s[4][2];
#pragma unroll
        for (int mi = 0; mi < 4; ++mi)
#pragma unroll
            for (int nq = 0; nq < 2; ++nq)
                s[mi][nq] = (f32x4){0.f, 0.f, 0.f, 0.f};
#pragma unroll
        for (int kk = 0; kk < 4; ++kk) {
            bf16x8 kf[4];
#pragma unroll
            for (int mi = 0; mi < 4; ++mi) {
                int row = mi * 16 + lr;
                int byte = (row * 256 + kk * 64 + lg * 16) ^ ((row & 7) << 4);
                kf[mi] = *(const bf16x8*)((const char*)Kl + kb + byte);
            }
            __builtin_amdgcn_s_setprio(1);
#pragma unroll
            for (int mi = 0; mi < 4; ++mi)
#pragma unroll
                for (int nq = 0; nq < 2; ++nq)
                    s[mi][nq] = __builtin_amdgcn_mfma_f32_16x16x32_bf16(kf[mi], qf[nq][kk], s[mi][nq], 0, 0, 0);
            __builtin_amdgcn_s_setprio(0);
        }

        float fac[2];
        bool doresc[2];
#pragma unroll
        for (int nq = 0; nq < 2; ++nq) {
            float mx = -3.0e38f;
#pragma unroll
            for (int mi = 0; mi < 4; ++mi)
#pragma unroll
                for (int r = 0; r < 4; ++r)
                    mx = fmaxf(mx, s[mi][nq][r]);
            mx = fmaxf(mx, __shfl_xor(mx, 16));
            mx = fmaxf(mx, __shfl_xor(mx, 32));
            float mxl = mx * cl2;
            float mr = m_run[nq];
            if (__any(mxl - mr > 8.0f)) {
                float mn = fmaxf(mr, mxl);
                fac[nq] = __builtin_amdgcn_exp2f(mr - mn);
                m_run[nq] = mn;
                doresc[nq] = true;
            } else {
                fac[nq] = 1.0f;
                doresc[nq] = false;
            }
            const float nmn = -m_run[nq];
            float sum = 0.f;
            const int q = wave * 32 + nq * 16 + lr;
#pragma unroll
            for (int mi = 0; mi < 4; ++mi) {
                float p0 = __builtin_amdgcn_exp2f(__builtin_fmaf(s[mi][nq][0], cl2, nmn));
                float p1 = __builtin_amdgcn_exp2f(__builtin_fmaf(s[mi][nq][1], cl2, nmn));
                float p2 = __builtin_amdgcn_exp2f(__builtin_fmaf(s[mi][nq][2], cl2, nmn));
                float p3 = __builtin_amdgcn_exp2f(__builtin_fmaf(s[mi][nq][3], cl2, nmn));
                sum += (p0 + p1) + (p2 + p3);
                uint2 pk;
                pk.x = cvt_pk_bf16(p0, p1);
                pk.y = cvt_pk_bf16(p2, p3);
                int byte = (q * 128 + (mi * 16 + lg * 4) * 2) ^ ((q & 7) << 4);
                *(uint2*)((char*)Pl + byte) = pk;
            }
            sum += __shfl_xor(sum, 16);
            sum += __shfl_xor(sum, 32);
            l_run[nq] = l_run[nq] * fac[nq] + sum;
        }

#pragma unroll
        for (int mo = 0; mo < 2; ++mo)
            if (doresc[mo]) {
#pragma unroll
                for (int r = 0; r < 4; ++r) {
                    int src = (lane & 48) | (lg * 4 + r);
                    float f = __shfl(fac[mo], src);
#pragma unroll
                    for (int nd = 0; nd < 8; ++nd)
                        o[mo][nd][r] *= f;
                }
            }

#pragma unroll
        for (int kk = 0; kk < 2; ++kk) {
            bf16x8 pf[2], vf[8];
#pragma unroll
            for (int mo = 0; mo < 2; ++mo) {
                int q = wave * 32 + mo * 16 + lr;
                int byte = (q * 128 + kk * 64 + lg * 16) ^ ((q & 7) << 4);
                pf[mo] = *(const bf16x8*)((const char*)Pl + byte);
            }
#pragma unroll
            for (int nd = 0; nd < 8; ++nd) {
                int drow = nd * 16 + lr;
                int byte = (drow * 128 + kk * 64 + lg * 16) ^ ((drow & 7) << 4);
                vf[nd] = *(const bf16x8*)((const char*)Vl + kb + byte);
            }
            __builtin_amdgcn_s_setprio(1);
#pragma unroll
            for (int mo = 0; mo < 2; ++mo)
#pragma unroll
                for (int nd = 0; nd < 8; ++nd)
                    o[mo][nd] = __builtin_amdgcn_mfma_f32_16x16x32_bf16(pf[mo], vf[nd], o[mo][nd], 0, 0, 0);
            __builtin_amdgcn_s_setprio(0);
        }
        __builtin_amdgcn_s_barrier(); SB();
    }

#pragma unroll
    for (int mo = 0; mo < 2; ++mo) {
        float rl[4];
#pragma unroll
        for (int r = 0; r < 4; ++r) {
            int src = (lane & 48) | (lg * 4 + r);
            rl[r] = 1.0f / __shfl(l_run[mo], src);
        }
#pragma unroll
        for (int nd = 0; nd < 8; ++nd)
#pragma unroll
            for (int r = 0; r < 4; ++r) {
                int q = qtok + mo * 16 + lg * 4 + r;
                ctx[(size_t)q * 1024 + h * 128 + nd * 16 + lr] = f2bf(o[mo][nd][r] * rl[r]);
            }
    }
}

// ---------------- in-place LayerNorm over D=1024 ----------------
__global__ __launch_bounds__(256) void k_ln(float* __restrict__ io,
                                            const float* __restrict__ gamma,
                                            const float* __restrict__ beta)
{
    __shared__ float bs[4], bss[4];
    const int row = blockIdx.x;
    const int t = threadIdx.x;
    float4 v = ((const float4*)&io[(size_t)row * 1024])[t];
    float s = (v.x + v.y) + (v.z + v.w);
    float ss = (v.x * v.x + v.y * v.y) + (v.z * v.z + v.w * v.w);
#pragma unroll
    for (int off = 32; off >= 1; off >>= 1) {
        s += __shfl_xor(s, off);
        ss += __shfl_xor(ss, off);
    }
    if ((t & 63) == 0) { bs[t >> 6] = s; bss[t >> 6] = ss; }
    __syncthreads();
    s = (bs[0] + bs[1]) + (bs[2] + bs[3]);
    ss = (bss[0] + bss[1]) + (bss[2] + bss[3]);
    const float mu = s * (1.f / 1024.f);
    const float var = ss * (1.f / 1024.f) - mu * mu;
    const float rs = rsqrtf(var + 1e-5f);
    float4 g = ((const float4*)gamma)[t];
    float4 b = ((const float4*)beta)[t];
    float4 ov;
    ov.x = (v.x - mu) * rs * g.x + b.x;
    ov.y = (v.y - mu) * rs * g.y + b.y;
    ov.z = (v.z - mu) * rs * g.z + b.z;
    ov.w = (v.w - mu) * rs * g.w + b.w;
    ((float4*)&io[(size_t)row * 1024])[t] = ov;
}

extern "C" void kernel_launch(void* const* d_in, const int* in_sizes, int n_in,
                              void* d_out, int out_size, void* d_ws, size_t ws_size,
                              hipStream_t stream)
{
    const float* val   = (const float*)d_in[0];
    const float* w_qkv = (const float*)d_in[1];
    const float* b_qkv = (const float*)d_in[2];
    const float* w_out = (const float*)d_in[3];
    const float* b_out = (const float*)d_in[4];
    const float* ln_g  = (const float*)d_in[5];
    const float* ln_b  = (const float*)d_in[6];
    float* out = (float*)d_out;

    char* ws = (char*)d_ws;
    unsigned short* qk     = (unsigned short*)(ws + 0);          // 33,554,432 B
    unsigned short* vTb    = (unsigned short*)(ws + 33554432);   // 16,777,216 B
    unsigned short* ctx    = (unsigned short*)(ws + 50331648);   // 16,777,216 B
    unsigned short* w_outT = (unsigned short*)(ws + 67108864);   //  2,097,152 B
    unsigned short* w_qkvT = (unsigned short*)(ws + 69206016);   //  6,291,456 B
    unsigned short* valb   = (unsigned short*)(ws + 75497472);   // 16,777,216 B

    k_convert<<<8192, 256, 0, stream>>>(val, valb, 2097152);
    k_transpose<<<dim3(48, 16), 256, 0, stream>>>(w_qkv, w_qkvT, 1024, 3072);
    k_transpose<<<dim3(16, 16), 256, 0, stream>>>(w_out, w_outT, 1024, 1024);
    k_gemm1<<<768, 512, 0, stream>>>(valb, w_qkvT, b_qkv, qk, vTb);
    k_attn<<<dim3(8, 64), 256, 0, stream>>>(qk, vTb, ctx);
    k_gemm2<<<dim3(8, 64), 256, 0, stream>>>(ctx, w_outT, b_out, val, out, 1024);
    k_ln<<<8192, 256, 0, stream>>>(out, ln_g, ln_b);
}

// Round 8
// 155.112 us; speedup vs baseline: 1.4200x; 1.1153x over previous
//
#include <hip/hip_runtime.h>
#include <hip/hip_bf16.h>
#include <stdint.h>

// Problem: B=2, S=4096, D=1024, H=8, DH=128, W=1024, nb=4, M=B*S=8192
// Pipeline: convert/transpose -> GEMM1 (256x128, reg-cached frags, 3-buf LDS,
//           1 barrier + counted vmcnt per K-tile) -> flash attention ->
//           GEMM2 (same template, +bias+residual) -> in-place LayerNorm.

typedef float f32x4 __attribute__((ext_vector_type(4)));
typedef __bf16 bf16x8 __attribute__((ext_vector_type(8)));

static __device__ __forceinline__ unsigned short f2bf(float f) {
    unsigned int u = __builtin_bit_cast(unsigned int, f);
    u += 0x7fffu + ((u >> 16) & 1u);
    return (unsigned short)(u >> 16);
}

static __device__ __forceinline__ unsigned cvt_pk_bf16(float lo, float hi) {
    unsigned r;
    asm("v_cvt_pk_bf16_f32 %0, %1, %2" : "=v"(r) : "v"(lo), "v"(hi));
    return r;
}

static __device__ __forceinline__ void gload_lds16(const void* g, void* l) {
    __builtin_amdgcn_global_load_lds(
        (__attribute__((address_space(1))) void*)(g),
        (__attribute__((address_space(3))) void*)(l), 16, 0, 0);
}

#define VMCNT(n) asm volatile("s_waitcnt vmcnt(" #n ")" ::: "memory")
#define SB() __builtin_amdgcn_sched_barrier(0)

// ---------------- convert f32 -> bf16 ----------------
__global__ __launch_bounds__(256) void k_convert(const float* __restrict__ in,
                                                 unsigned short* __restrict__ out,
                                                 int n4) {
    int i = blockIdx.x * 256 + threadIdx.x;
    if (i >= n4) return;
    float4 v = ((const float4*)in)[i];
    ushort4 o;
    o.x = f2bf(v.x); o.y = f2bf(v.y); o.z = f2bf(v.z); o.w = f2bf(v.w);
    ((ushort4*)out)[i] = o;
}

// ---------------- transpose f32 [R][C] -> bf16 [C][R] ----------------
__global__ __launch_bounds__(256) void k_transpose(const float* __restrict__ in,
                                                   unsigned short* __restrict__ out,
                                                   int R, int C) {
    __shared__ float tile[64][65];
    const int rt = blockIdx.y * 64, ct = blockIdx.x * 64;
    const int t = threadIdx.x;
#pragma unroll
    for (int i = 0; i < 4; ++i) {
        int fid = i * 256 + t;
        int r = fid >> 4;
        int c = (fid & 15) << 2;
        float4 v = *(const float4*)&in[(size_t)(rt + r) * C + ct + c];
        tile[r][c] = v.x; tile[r][c + 1] = v.y; tile[r][c + 2] = v.z; tile[r][c + 3] = v.w;
    }
    __syncthreads();
#pragma unroll
    for (int i = 0; i < 4; ++i) {
        int fid = i * 256 + t;
        int c = fid >> 4;
        int r0 = (fid & 15) << 2;
        ushort4 o;
        o.x = f2bf(tile[r0][c]);     o.y = f2bf(tile[r0 + 1][c]);
        o.z = f2bf(tile[r0 + 2][c]); o.w = f2bf(tile[r0 + 3][c]);
        *(ushort4*)&out[(size_t)(ct + c) * R + rt + r0] = o;
    }
}

// ======== GEMM: 256x128 tile, BK=64, reg-cached fragments, 3-buffer LDS ========
// Round-7 lesson: the 8-phase variant was LDS-BW-bound (af/bf re-read per
// quadrant = 304KB LDS traffic per K-tile -> 26% ceiling = measured 27%).
// Here: af[4][2] cached in regs for the whole K-tile, bf per nh-half ->
// 16KB/wave/K-tile (exact need, 176KB/block incl. stage writes -> ~45% ceiling).
// Triple-buffered LDS (144KB): ONE barrier + ONE counted VMCNT(6) per K-tile;
// stages issued 2 K-tiles ahead (~2 compute phases of latency cover).
// Swizzle rule #21: linear gload_lds dest + inverse-swizzled global source +
// swizzled ds_read (XOR involution on 16B blocks). VGPR: 64 acc + 32 af +
// 16 bf + addr ~= 120 < empirical 128 cap (rounds 4-6).
// MODE 0: qkv -> Q/K row-major [m][2048] + V^T [head][d][x].  NTILES=24.
// MODE 1: out = A*Bt^T + bias + resid (fp32).                 NTILES=8.
template <int MODE, int NTILES>
__global__ __launch_bounds__(512) void k_gemm(
    const unsigned short* __restrict__ A,
    const unsigned short* __restrict__ Bt,
    const float* __restrict__ bias,
    const float* __restrict__ resid,
    unsigned short* __restrict__ out_qk,
    unsigned short* __restrict__ out_vT,
    float* __restrict__ out_f)
{
    __shared__ __align__(16) char smem[147456];  // 3 x (A 32KB + B 16KB)
    const int t = threadIdx.x;
    const int wave = t >> 6, lane = t & 63;
    const int lr = lane & 15, lg = lane >> 4;
    const int wr = wave >> 1, wc = wave & 1;     // 4M x 2N wave grid

    // XCD swizzle: 32*NTILES blocks -> 4*NTILES contiguous per XCD
    const int lid = blockIdx.x;
    const int swz = (lid & 7) * (4 * NTILES) + (lid >> 3);
    const int tile_m = (swz / NTILES) * 256;
    const int tile_n = (swz % NTILES) * 128;

    const int srow = lane >> 3;                  // row within 8-row slab
    const int sblk = (lane & 7) ^ srow;          // inverse-swizzled 16B block

    f32x4 acc[4][4];
#pragma unroll
    for (int i = 0; i < 4; ++i)
#pragma unroll
        for (int j = 0; j < 4; ++j)
            acc[i][j] = (f32x4){0.f, 0.f, 0.f, 0.f};

    // stage half h of K-tile kt into buffer buf: 2 A + 1 B gload_lds /thread
    auto stage2 = [&](int kt, int buf, int h) {
#pragma unroll
        for (int i = 0; i < 2; ++i) {
            int r = h * 128 + i * 64 + wave * 8 + srow;
            int dst = buf * 49152 + h * 16384 + i * 8192 + wave * 1024 + lane * 16;
            gload_lds16(&A[(size_t)(tile_m + r) * 1024 + kt * 64 + sblk * 8], smem + dst);
        }
        int rb = h * 64 + wave * 8 + srow;
        int dstb = buf * 49152 + 32768 + h * 8192 + wave * 1024 + lane * 16;
        gload_lds16(&Bt[(size_t)(tile_n + rb) * 1024 + kt * 64 + sblk * 8], smem + dstb);
    };

    // prologue: K-tiles 0,1 in flight (12 loads/thread)
    stage2(0, 0, 0); stage2(0, 0, 1);
    stage2(1, 1, 0); stage2(1, 1, 1);

    bf16x8 af[4][2], bf[2][2];

    for (int kt = 0; kt < 16; ++kt) {
        const int buf = kt % 3;
        // buf[kt%3]'s 6 loads landed (6 newer for kt+1 may remain in flight);
        // barrier also closes tile kt-1's reads of buf[(kt+2)%3] before we
        // overwrite it below.
        if (kt == 15) { VMCNT(0); } else { VMCNT(6); }
        SB(); __builtin_amdgcn_s_barrier(); SB();

        const int abase = buf * 49152;
        const int bbase = buf * 49152 + 32768;

        // af: whole wave M-band (64 rows x K64), cached for the K-tile
#pragma unroll
        for (int mi = 0; mi < 4; ++mi) {
            const int row = wr * 64 + mi * 16 + lr;
#pragma unroll
            for (int kk = 0; kk < 2; ++kk)
                af[mi][kk] = *(const bf16x8*)(smem + abase + row * 128 +
                                (((kk * 4 + lg) ^ (row & 7)) << 4));
        }
        // bf half nh=0
#pragma unroll
        for (int ni = 0; ni < 2; ++ni) {
            const int row = wc * 64 + ni * 16 + lr;
#pragma unroll
            for (int kk = 0; kk < 2; ++kk)
                bf[ni][kk] = *(const bf16x8*)(smem + bbase + row * 128 +
                                (((kk * 4 + lg) ^ (row & 7)) << 4));
        }
        if (kt < 14) stage2(kt + 2, (kt + 2) % 3, 0);

        __builtin_amdgcn_s_setprio(1);
#pragma unroll
        for (int kk = 0; kk < 2; ++kk)
#pragma unroll
            for (int mi = 0; mi < 4; ++mi)
#pragma unroll
                for (int ni = 0; ni < 2; ++ni)
                    acc[mi][ni] = __builtin_amdgcn_mfma_f32_16x16x32_bf16(
                        af[mi][kk], bf[ni][kk], acc[mi][ni], 0, 0, 0);
        __builtin_amdgcn_s_setprio(0);

        // bf half nh=1 (reuses bf regs; af stays cached)
#pragma unroll
        for (int ni = 0; ni < 2; ++ni) {
            const int row = wc * 64 + 32 + ni * 16 + lr;
#pragma unroll
            for (int kk = 0; kk < 2; ++kk)
                bf[ni][kk] = *(const bf16x8*)(smem + bbase + row * 128 +
                                (((kk * 4 + lg) ^ (row & 7)) << 4));
        }
        if (kt < 14) stage2(kt + 2, (kt + 2) % 3, 1);

        __builtin_amdgcn_s_setprio(1);
#pragma unroll
        for (int kk = 0; kk < 2; ++kk)
#pragma unroll
            for (int mi = 0; mi < 4; ++mi)
#pragma unroll
                for (int ni = 0; ni < 2; ++ni)
                    acc[mi][2 + ni] = __builtin_amdgcn_mfma_f32_16x16x32_bf16(
                        af[mi][kk], bf[ni][kk], acc[mi][2 + ni], 0, 0, 0);
        __builtin_amdgcn_s_setprio(0);
    }

    // ---- epilogue: D row(m) = lg*4+reg, col(n) = lr ----
#pragma unroll
    for (int J = 0; J < 4; ++J) {
        const int n = tile_n + wc * 64 + J * 16 + lr;
        const float bv = bias[n];
#pragma unroll
        for (int I = 0; I < 4; ++I) {
            const int m0 = tile_m + wr * 64 + I * 16 + lg * 4;
            f32x4 v = acc[I][J];
            if (MODE == 0) {
                if (n < 2048) {          // Q,K region: row-major [m][2048]
#pragma unroll
                    for (int r = 0; r < 4; ++r)
                        out_qk[(size_t)(m0 + r) * 2048 + n] = f2bf(v[r] + bv);
                } else {                 // V region: transposed [head][d][x]
                    int hd = (n - 2048) >> 7;
                    int dd = (n - 2048) & 127;
                    int bn = m0 >> 10;
                    int x0 = m0 & 1023;
                    ushort4 o;
                    o.x = f2bf(v[0] + bv); o.y = f2bf(v[1] + bv);
                    o.z = f2bf(v[2] + bv); o.w = f2bf(v[3] + bv);
                    *(ushort4*)&out_vT[((size_t)(bn * 8 + hd) * 128 + dd) * 1024 + x0] = o;
                }
            } else {
#pragma unroll
                for (int r = 0; r < 4; ++r) {
                    size_t idx = (size_t)(m0 + r) * 1024 + n;
                    out_f[idx] = v[r] + bv + resid[idx];
                }
            }
        }
    }
}

// ---------------- flash attention (v3: gload_lds dbuf, counted vmcnt) ----------------
__global__ __launch_bounds__(256, 2) void k_attn(
    const unsigned short* __restrict__ qk,   // [8192][2048] bf16 (Q | K)
    const unsigned short* __restrict__ vT,   // [64 heads][128 d][1024 x] bf16
    unsigned short* __restrict__ ctx)        // [8192][1024] bf16
{
    __shared__ __align__(16) unsigned short Kl[2 * 64 * 128];
    __shared__ __align__(16) unsigned short Vl[2 * 128 * 64];
    __shared__ __align__(16) unsigned short Pl[128 * 64];
    const int t = threadIdx.x;
    const int wave = t >> 6, lane = t & 63;
    const int lr = lane & 15, lg = lane >> 4;

    const int lid = blockIdx.y * gridDim.x + blockIdx.x;
    const int xcd = lid & 7, slot = lid >> 3;
    const int head = xcd * 8 + (slot & 7);
    const int qblk = slot >> 3;

    const int h = head & 7;
    const int tok0 = (head >> 3) * 1024;
    const int qtok = tok0 + qblk * 128 + wave * 32;
    const float cl2 = 0.08838834764831845f * 1.44269504088896f;

    const unsigned short* kbase = &qk[(size_t)tok0 * 2048 + 1024 + h * 128];
    const unsigned short* vhead = &vT[(size_t)head * 128 * 1024];

    auto stage = [&](int x0, int buf) {
        unsigned short* Kb = (unsigned short*)((char*)Kl + buf * 16384);
        unsigned short* Vb = (unsigned short*)((char*)Vl + buf * 16384);
#pragma unroll
        for (int i = 0; i < 4; ++i) {
            int x = i * 16 + wave * 4 + (lane >> 4);
            int ck = (lane & 15) ^ (x & 7);
            gload_lds16(&kbase[(size_t)(x0 + x) * 2048 + ck * 8], &Kb[i * 2048 + wave * 512]);
            int d = i * 32 + wave * 8 + (lane >> 3);
            int cv = (lane & 7) ^ (d & 7);
            gload_lds16(&vhead[(size_t)d * 1024 + x0 + cv * 8], &Vb[i * 2048 + wave * 512]);
        }
    };

    bf16x8 qf[2][4];
#pragma unroll
    for (int nq = 0; nq < 2; ++nq)
#pragma unroll
        for (int kk = 0; kk < 4; ++kk)
            qf[nq][kk] = *(const bf16x8*)&qk[(size_t)(qtok + 16 * nq + lr) * 2048 + h * 128 + kk * 32 + lg * 8];

    f32x4 o[2][8];
#pragma unroll
    for (int a = 0; a < 2; ++a)
#pragma unroll
        for (int b = 0; b < 8; ++b)
            o[a][b] = (f32x4){0.f, 0.f, 0.f, 0.f};
    float m_run[2] = {-3.0e38f, -3.0e38f};
    float l_run[2] = {0.f, 0.f};

    stage(0, 0);

    for (int tile = 0; tile < 16; ++tile) {
        const int kb = (tile & 1) * 16384;
        if (tile < 15) {
            stage((tile + 1) * 64, (tile + 1) & 1);
            VMCNT(8);
        } else {
            VMCNT(0);
        }
        SB(); __builtin_amdgcn_s_barrier(); SB();

        f32x4 s[4][2];
#pragma unroll
        for (int mi = 0; mi < 4; ++mi)
#pragma unroll
            for (int nq = 0; nq < 2; ++nq)
                s[mi][nq] = (f32x4){0.f, 0.f, 0.f, 0.f};
#pragma unroll
        for (int kk = 0; kk < 4; ++kk) {
            bf16x8 kf[4];
#pragma unroll
            for (int mi = 0; mi < 4; ++mi) {
                int row = mi * 16 + lr;
                int byte = (row * 256 + kk * 64 + lg * 16) ^ ((row & 7) << 4);
                kf[mi] = *(const bf16x8*)((const char*)Kl + kb + byte);
            }
            __builtin_amdgcn_s_setprio(1);
#pragma unroll
            for (int mi = 0; mi < 4; ++mi)
#pragma unroll
                for (int nq = 0; nq < 2; ++nq)
                    s[mi][nq] = __builtin_amdgcn_mfma_f32_16x16x32_bf16(kf[mi], qf[nq][kk], s[mi][nq], 0, 0, 0);
            __builtin_amdgcn_s_setprio(0);
        }

        float fac[2];
        bool doresc[2];
#pragma unroll
        for (int nq = 0; nq < 2; ++nq) {
            float mx = -3.0e38f;
#pragma unroll
            for (int mi = 0; mi < 4; ++mi)
#pragma unroll
                for (int r = 0; r < 4; ++r)
                    mx = fmaxf(mx, s[mi][nq][r]);
            mx = fmaxf(mx, __shfl_xor(mx, 16));
            mx = fmaxf(mx, __shfl_xor(mx, 32));
            float mxl = mx * cl2;
            float mr = m_run[nq];
            if (__any(mxl - mr > 8.0f)) {
                float mn = fmaxf(mr, mxl);
                fac[nq] = __builtin_amdgcn_exp2f(mr - mn);
                m_run[nq] = mn;
                doresc[nq] = true;
            } else {
                fac[nq] = 1.0f;
                doresc[nq] = false;
            }
            const float nmn = -m_run[nq];
            float sum = 0.f;
            const int q = wave * 32 + nq * 16 + lr;
#pragma unroll
            for (int mi = 0; mi < 4; ++mi) {
                float p0 = __builtin_amdgcn_exp2f(__builtin_fmaf(s[mi][nq][0], cl2, nmn));
                float p1 = __builtin_amdgcn_exp2f(__builtin_fmaf(s[mi][nq][1], cl2, nmn));
                float p2 = __builtin_amdgcn_exp2f(__builtin_fmaf(s[mi][nq][2], cl2, nmn));
                float p3 = __builtin_amdgcn_exp2f(__builtin_fmaf(s[mi][nq][3], cl2, nmn));
                sum += (p0 + p1) + (p2 + p3);
                uint2 pk;
                pk.x = cvt_pk_bf16(p0, p1);
                pk.y = cvt_pk_bf16(p2, p3);
                int byte = (q * 128 + (mi * 16 + lg * 4) * 2) ^ ((q & 7) << 4);
                *(uint2*)((char*)Pl + byte) = pk;
            }
            sum += __shfl_xor(sum, 16);
            sum += __shfl_xor(sum, 32);
            l_run[nq] = l_run[nq] * fac[nq] + sum;
        }

#pragma unroll
        for (int mo = 0; mo < 2; ++mo)
            if (doresc[mo]) {
#pragma unroll
                for (int r = 0; r < 4; ++r) {
                    int src = (lane & 48) | (lg * 4 + r);
                    float f = __shfl(fac[mo], src);
#pragma unroll
                    for (int nd = 0; nd < 8; ++nd)
                        o[mo][nd][r] *= f;
                }
            }

#pragma unroll
        for (int kk = 0; kk < 2; ++kk) {
            bf16x8 pf[2], vf[8];
#pragma unroll
            for (int mo = 0; mo < 2; ++mo) {
                int q = wave * 32 + mo * 16 + lr;
                int byte = (q * 128 + kk * 64 + lg * 16) ^ ((q & 7) << 4);
                pf[mo] = *(const bf16x8*)((const char*)Pl + byte);
            }
#pragma unroll
            for (int nd = 0; nd < 8; ++nd) {
                int drow = nd * 16 + lr;
                int byte = (drow * 128 + kk * 64 + lg * 16) ^ ((drow & 7) << 4);
                vf[nd] = *(const bf16x8*)((const char*)Vl + kb + byte);
            }
            __builtin_amdgcn_s_setprio(1);
#pragma unroll
            for (int mo = 0; mo < 2; ++mo)
#pragma unroll
                for (int nd = 0; nd < 8; ++nd)
                    o[mo][nd] = __builtin_amdgcn_mfma_f32_16x16x32_bf16(pf[mo], vf[nd], o[mo][nd], 0, 0, 0);
            __builtin_amdgcn_s_setprio(0);
        }
        __builtin_amdgcn_s_barrier(); SB();
    }

#pragma unroll
    for (int mo = 0; mo < 2; ++mo) {
        float rl[4];
#pragma unroll
        for (int r = 0; r < 4; ++r) {
            int src = (lane & 48) | (lg * 4 + r);
            rl[r] = 1.0f / __shfl(l_run[mo], src);
        }
#pragma unroll
        for (int nd = 0; nd < 8; ++nd)
#pragma unroll
            for (int r = 0; r < 4; ++r) {
                int q = qtok + mo * 16 + lg * 4 + r;
                ctx[(size_t)q * 1024 + h * 128 + nd * 16 + lr] = f2bf(o[mo][nd][r] * rl[r]);
            }
    }
}

// ---------------- in-place LayerNorm over D=1024 ----------------
__global__ __launch_bounds__(256) void k_ln(float* __restrict__ io,
                                            const float* __restrict__ gamma,
                                            const float* __restrict__ beta)
{
    __shared__ float bs[4], bss[4];
    const int row = blockIdx.x;
    const int t = threadIdx.x;
    float4 v = ((const float4*)&io[(size_t)row * 1024])[t];
    float s = (v.x + v.y) + (v.z + v.w);
    float ss = (v.x * v.x + v.y * v.y) + (v.z * v.z + v.w * v.w);
#pragma unroll
    for (int off = 32; off >= 1; off >>= 1) {
        s += __shfl_xor(s, off);
        ss += __shfl_xor(ss, off);
    }
    if ((t & 63) == 0) { bs[t >> 6] = s; bss[t >> 6] = ss; }
    __syncthreads();
    s = (bs[0] + bs[1]) + (bs[2] + bs[3]);
    ss = (bss[0] + bss[1]) + (bss[2] + bss[3]);
    const float mu = s * (1.f / 1024.f);
    const float var = ss * (1.f / 1024.f) - mu * mu;
    const float rs = rsqrtf(var + 1e-5f);
    float4 g = ((const float4*)gamma)[t];
    float4 b = ((const float4*)beta)[t];
    float4 ov;
    ov.x = (v.x - mu) * rs * g.x + b.x;
    ov.y = (v.y - mu) * rs * g.y + b.y;
    ov.z = (v.z - mu) * rs * g.z + b.z;
    ov.w = (v.w - mu) * rs * g.w + b.w;
    ((float4*)&io[(size_t)row * 1024])[t] = ov;
}

extern "C" void kernel_launch(void* const* d_in, const int* in_sizes, int n_in,
                              void* d_out, int out_size, void* d_ws, size_t ws_size,
                              hipStream_t stream)
{
    const float* val   = (const float*)d_in[0];
    const float* w_qkv = (const float*)d_in[1];
    const float* b_qkv = (const float*)d_in[2];
    const float* w_out = (const float*)d_in[3];
    const float* b_out = (const float*)d_in[4];
    const float* ln_g  = (const float*)d_in[5];
    const float* ln_b  = (const float*)d_in[6];
    float* out = (float*)d_out;

    char* ws = (char*)d_ws;
    unsigned short* qk     = (unsigned short*)(ws + 0);          // 33,554,432 B
    unsigned short* vTb    = (unsigned short*)(ws + 33554432);   // 16,777,216 B
    unsigned short* ctx    = (unsigned short*)(ws + 50331648);   // 16,777,216 B
    unsigned short* w_outT = (unsigned short*)(ws + 67108864);   //  2,097,152 B
    unsigned short* w_qkvT = (unsigned short*)(ws + 69206016);   //  6,291,456 B
    unsigned short* valb   = (unsigned short*)(ws + 75497472);   // 16,777,216 B

    k_convert<<<8192, 256, 0, stream>>>(val, valb, 2097152);
    k_transpose<<<dim3(48, 16), 256, 0, stream>>>(w_qkv, w_qkvT, 1024, 3072);
    k_transpose<<<dim3(16, 16), 256, 0, stream>>>(w_out, w_outT, 1024, 1024);
    k_gemm<0, 24><<<768, 512, 0, stream>>>(valb, w_qkvT, b_qkv, nullptr, qk, vTb, nullptr);
    k_attn<<<dim3(8, 64), 256, 0, stream>>>(qk, vTb, ctx);
    k_gemm<1, 8><<<256, 512, 0, stream>>>(ctx, w_outT, b_out, val, nullptr, nullptr, out);
    k_ln<<<8192, 256, 0, stream>>>(out, ln_g, ln_b);
}